// Round 12
// baseline (91.682 us; speedup 1.0000x reference)
//
#include <hip/hip_runtime.h>
#include <hip/hip_bf16.h>

#define B_ROWS 4096
#define D_FEAT 512

typedef short s16x8 __attribute__((ext_vector_type(8)));
typedef float f32x4 __attribute__((ext_vector_type(4)));

__device__ inline float waveReduceSum(float v) {
#pragma unroll
    for (int off = 32; off > 0; off >>= 1) v += __shfl_xor(v, off);
    return v;
}

// ---- prep: fp32->bf16 convert + sqnorm(rounded) + ws init; blocks 0..15 also do focal+KD ----
__global__ __launch_bounds__(256) void prep_kernel(const float* __restrict__ feat,
                                                   const float* __restrict__ logits,
                                                   const int* __restrict__ labels,
                                                   const float* __restrict__ soft,
                                                   short* __restrict__ featbf,
                                                   float* __restrict__ sqn,
                                                   unsigned* __restrict__ posmax,
                                                   float* __restrict__ negminf,
                                                   float* __restrict__ fpart,
                                                   float* __restrict__ kpart) {
    const int bid = blockIdx.x, tid = threadIdx.x;
    const int wave = tid >> 6, lane = tid & 63;
    const int row = bid * 4 + wave;

    const float* p = feat + (size_t)row * D_FEAT + lane * 8;
    float4 a = *(const float4*)p;
    float4 b = *(const float4*)(p + 4);
    float vals[8] = {a.x, a.y, a.z, a.w, b.x, b.y, b.z, b.w};
    short outv[8];
    float s = 0.f;
#pragma unroll
    for (int j = 0; j < 8; ++j) {
        __hip_bfloat16 h = __float2bfloat16(vals[j]);
        outv[j] = *(short*)&h;
        float xb = __bfloat162float(h);
        s = fmaf(xb, xb, s);
    }
    *(s16x8*)(featbf + (size_t)row * D_FEAT + lane * 8) = *(s16x8*)outv;
    s = waveReduceSum(s);
    if (lane == 0) sqn[row] = s;

    if (tid < 4) posmax[bid * 4 + tid] = 0u;
    else if (tid < 8) negminf[bid * 4 + tid - 4] = 1e12f;

    if (bid < 16) {
        int i = bid * 256 + tid;
        float l0 = logits[2 * i], l1 = logits[2 * i + 1];

        float m = fmaxf(l0, l1);
        float lse = m + logf(expf(l0 - m) + expf(l1 - m));
        float lp = (labels[i] ? l1 : l0) - lse;
        float ce = -lp;
        float pt = expf(lp);
        float om = 1.f - pt;
        float focal = om * om * ce;

        const float Tinv = 1.f / 3.f;
        float s0 = l0 * Tinv, s1 = l1 * Tinv;
        float ms = fmaxf(s0, s1);
        float lses = ms + logf(expf(s0 - ms) + expf(s1 - ms));
        float sl0 = s0 - lses, sl1 = s1 - lses;
        float t0 = logf(soft[2 * i] + 1e-8f) * Tinv;
        float t1 = logf(soft[2 * i + 1] + 1e-8f) * Tinv;
        float mt = fmaxf(t0, t1);
        float lset = mt + logf(expf(t0 - mt) + expf(t1 - mt));
        float tl0 = t0 - lset, tl1 = t1 - lset;
        float p0 = expf(tl0), p1 = expf(tl1);
        float kd = p0 * (tl0 - sl0) + p1 * (tl1 - sl1);

        float fs = waveReduceSum(focal);
        float ks = waveReduceSum(kd);
        __shared__ float sf[4], sk[4];
        if (lane == 0) { sf[wave] = fs; sk[wave] = ks; }
        __syncthreads();
        if (tid == 0) {
            fpart[bid] = sf[0] + sf[1] + sf[2] + sf[3];
            kpart[bid] = sk[0] + sk[1] + sk[2] + sk[3];
        }
    }
}

// ---- pairwise d^2: wave-independent, LDS-free K-loop, explicit register dbuf ----
// Block = 4 waves (256 thr); wave = own 64x64 tile; block covers 64 rows x 256 cols.
// A and B fragments loaded DIRECTLY from global (featbf = 4MB, fits each XCD L2;
// block's A-row slice 4KB/kk stays L1-hot across the 4 waves). Manual 1-deep
// register double-buffer: load frags(kk+1) while MFMA(kk) -> L2 latency (~200-400cy)
// hides under the 16-MFMA window; NO barriers in the K-loop; waves slip freely.
// __launch_bounds__(256,3): ~170-reg cap -> room for 64 acc AGPR + ~64 VGPR dbuf,
// 12 waves/CU. XCD pin: colg = ((bid&7)<<1)|((bid>>3)&1) (bijective w/ rowg=bid>>4):
// each XCD round-robin group sees a 512-col B-band (512KB, L2-resident).
__global__ __launch_bounds__(256, 3) void pairwise_reg_kernel(const short* __restrict__ featbf,
                                                              const float* __restrict__ sqn,
                                                              const int* __restrict__ labels,
                                                              unsigned* __restrict__ posmax,
                                                              unsigned* __restrict__ negmin) {
    const int tid = threadIdx.x;
    const int bid = blockIdx.x;
    const int colg = ((bid & 7) << 1) | ((bid >> 3) & 1);  // 0..15
    const int rowg = bid >> 4;                             // 0..63
    const int wid = tid >> 6, lane = tid & 63;
    const int lo = lane & 15, hi = lane >> 4;

    // fragment pointers: A rows = rowg*64 + m*16 + lo; B cols = colg*256 + wid*64 + n*16 + lo
    const short* gA[4];
    const short* gB[4];
#pragma unroll
    for (int m = 0; m < 4; ++m)
        gA[m] = featbf + (size_t)(rowg * 64 + m * 16 + lo) * D_FEAT + hi * 8;
#pragma unroll
    for (int n = 0; n < 4; ++n)
        gB[n] = featbf + (size_t)(colg * 256 + wid * 64 + n * 16 + lo) * D_FEAT + hi * 8;

    f32x4 acc[4][4];
#pragma unroll
    for (int m = 0; m < 4; ++m)
#pragma unroll
        for (int n = 0; n < 4; ++n)
            acc[m][n] = (f32x4){0.f, 0.f, 0.f, 0.f};

    s16x8 a0[4], b0[4], a1[4], b1[4];
    // prologue: kk = 0 into buffer 0
#pragma unroll
    for (int m = 0; m < 4; ++m) a0[m] = *(const s16x8*)(gA[m]);
#pragma unroll
    for (int n = 0; n < 4; ++n) b0[n] = *(const s16x8*)(gB[n]);

#pragma unroll
    for (int kk = 0; kk < 16; kk += 2) {
        // issue loads for kk+1 (always valid: kk <= 14)
#pragma unroll
        for (int m = 0; m < 4; ++m) a1[m] = *(const s16x8*)(gA[m] + (kk + 1) * 32);
#pragma unroll
        for (int n = 0; n < 4; ++n) b1[n] = *(const s16x8*)(gB[n] + (kk + 1) * 32);
        // compute kk (waits only on a0/b0; a1/b1 stay in flight)
#pragma unroll
        for (int m = 0; m < 4; ++m)
#pragma unroll
            for (int n = 0; n < 4; ++n)
                acc[m][n] = __builtin_amdgcn_mfma_f32_16x16x32_bf16(a0[m], b0[n],
                                                                   acc[m][n], 0, 0, 0);
        // issue loads for kk+2 (guard tail)
        if (kk < 14) {
#pragma unroll
            for (int m = 0; m < 4; ++m) a0[m] = *(const s16x8*)(gA[m] + (kk + 2) * 32);
#pragma unroll
            for (int n = 0; n < 4; ++n) b0[n] = *(const s16x8*)(gB[n] + (kk + 2) * 32);
        }
        // compute kk+1
#pragma unroll
        for (int m = 0; m < 4; ++m)
#pragma unroll
            for (int n = 0; n < 4; ++n)
                acc[m][n] = __builtin_amdgcn_mfma_f32_16x16x32_bf16(a1[m], b1[n],
                                                                   acc[m][n], 0, 0, 0);
    }

    // ---- epilogue in d^2 domain (C/D layout m89: col = lo, row = hi*4 + reg) ----
    // 4 waves share the same 64 rows (different col strips): 16-lane shfl reduce ->
    // small LDS cross-wave reduce -> 1 atomic pair per row per block (65K total).
    __shared__ float redp[64][5], redn[64][5];
    int coln[4], labc[4];
    float sqc[4];
#pragma unroll
    for (int n = 0; n < 4; ++n) {
        coln[n] = colg * 256 + wid * 64 + n * 16 + lo;
        labc[n] = labels[coln[n]];
        sqc[n] = sqn[coln[n]];
    }
#pragma unroll
    for (int m = 0; m < 4; ++m) {
#pragma unroll
        for (int r = 0; r < 4; ++r) {
            int row_loc = m * 16 + hi * 4 + r;
            int row_g = rowg * 64 + row_loc;
            int labr = labels[row_g];
            float sqr = sqn[row_g];
            float pm = 0.f, nm = 1e12f;
#pragma unroll
            for (int n = 0; n < 4; ++n) {
                float d2 = fmaxf(sqr + fmaf(-2.f, acc[m][n][r], sqc[n]), 0.f);
                bool same = (labr == labc[n]);
                if (same) {
                    if (row_g != coln[n]) pm = fmaxf(pm, d2);
                } else {
                    nm = fminf(nm, d2);
                }
            }
#pragma unroll
            for (int off = 1; off < 16; off <<= 1) {
                pm = fmaxf(pm, __shfl_xor(pm, off));
                nm = fminf(nm, __shfl_xor(nm, off));
            }
            if (lo == 0) {
                redp[row_loc][wid] = pm;
                redn[row_loc][wid] = nm;
            }
        }
    }
    __syncthreads();
    if (tid < 64) {
        float p = fmaxf(fmaxf(redp[tid][0], redp[tid][1]),
                        fmaxf(redp[tid][2], redp[tid][3]));
        atomicMax(&posmax[rowg * 64 + tid], __float_as_uint(p));
    } else if (tid < 128) {
        int row = tid - 64;
        float nn = fminf(fminf(redn[row][0], redn[row][1]),
                         fminf(redn[row][2], redn[row][3]));
        atomicMin(&negmin[rowg * 64 + row], __float_as_uint(nn));
    }
}

// ---- final reduction + scalar combine (sqrt deferred to here; float32 outputs) ----
__global__ __launch_bounds__(256) void finalize_kernel(const unsigned* __restrict__ posmax,
                                                       const unsigned* __restrict__ negmin,
                                                       const float* __restrict__ fpart,
                                                       const float* __restrict__ kpart,
                                                       float* __restrict__ out) {
    int tid = threadIdx.x;
    float sum_pr = 0.f, sum_v = 0.f;
    for (int i = tid; i < B_ROWS; i += 256) {
        float p2 = __uint_as_float(posmax[i]);
        float n2 = __uint_as_float(negmin[i]);
        float v = (p2 > 0.f) ? 1.f : 0.f;
        sum_pr += fmaxf(sqrtf(p2) - sqrtf(n2) + 0.3f, 0.f) * v;
        sum_v += v;
    }
    sum_pr = waveReduceSum(sum_pr);
    sum_v = waveReduceSum(sum_v);
    __shared__ float sp[4], sv[4];
    int wave = tid >> 6, lane = tid & 63;
    if (lane == 0) { sp[wave] = sum_pr; sv[wave] = sum_v; }
    __syncthreads();
    if (tid == 0) {
        float spr = sp[0] + sp[1] + sp[2] + sp[3];
        float svv = sv[0] + sv[1] + sv[2] + sv[3];
        float fsum = 0.f, ksum = 0.f;
        for (int b = 0; b < 16; ++b) { fsum += fpart[b]; ksum += kpart[b]; }
        float focal = fsum / 4096.f;
        float kd = ksum / 4096.f * 9.f;  // * T^2
        float triplet = (svv > 0.f) ? spr / fmaxf(svv, 1.f) : 0.f;
        float total = focal + 0.5f * triplet + kd;
        out[0] = total;
        out[1] = focal;
        out[2] = triplet;
        out[3] = kd;
    }
}

extern "C" void kernel_launch(void* const* d_in, const int* in_sizes, int n_in,
                              void* d_out, int out_size, void* d_ws, size_t ws_size,
                              hipStream_t stream) {
    const float* logits = (const float*)d_in[0];
    const float* feat   = (const float*)d_in[1];
    const int*   labels = (const int*)d_in[2];
    const float* soft   = (const float*)d_in[3];

    char* ws = (char*)d_ws;
    unsigned* posmax = (unsigned*)ws;                    // 4096 u32 (d^2 bits)
    unsigned* negmin = (unsigned*)(ws + 16384);          // 4096 u32 (d^2 bits)
    float*    sqn    = (float*)(ws + 32768);             // 4096 f32
    float*    fpart  = (float*)(ws + 49152);             // 16 f32
    float*    kpart  = (float*)(ws + 49152 + 256);       // 16 f32
    short*    featbf = (short*)(ws + 65536);             // 4096*512 bf16 = 4 MB

    prep_kernel<<<1024, 256, 0, stream>>>(feat, logits, labels, soft, featbf, sqn,
                                          posmax, (float*)negmin, fpart, kpart);
    pairwise_reg_kernel<<<1024, 256, 0, stream>>>(featbf, sqn, labels, posmax, negmin);
    finalize_kernel<<<1, 256, 0, stream>>>(posmax, negmin, fpart, kpart,
                                           (float*)d_out);
}

// Round 13
// 44.543 us; speedup vs baseline: 2.0583x; 2.0583x over previous
//
#include <hip/hip_runtime.h>
#include <hip/hip_bf16.h>

#define B_ROWS 4096
#define D_FEAT 512

typedef short s16x8 __attribute__((ext_vector_type(8)));
typedef float f32x4 __attribute__((ext_vector_type(4)));

#define GLOAD_LDS16(gsrc, ldst)                                                        \
    __builtin_amdgcn_global_load_lds(                                                  \
        (const __attribute__((address_space(1))) void*)(gsrc),                         \
        (__attribute__((address_space(3))) void*)(ldst), 16, 0, 0)

__device__ inline float waveReduceSum(float v) {
#pragma unroll
    for (int off = 32; off > 0; off >>= 1) v += __shfl_xor(v, off);
    return v;
}

// ---- prep: fp32->bf16 convert + sqnorm(rounded) + ws init (incl. ticket);
//      blocks 0..15 also do focal+KD partial sums ----
__global__ __launch_bounds__(256) void prep_kernel(const float* __restrict__ feat,
                                                   const float* __restrict__ logits,
                                                   const int* __restrict__ labels,
                                                   const float* __restrict__ soft,
                                                   short* __restrict__ featbf,
                                                   float* __restrict__ sqn,
                                                   unsigned* __restrict__ posmax,
                                                   float* __restrict__ negminf,
                                                   float* __restrict__ fpart,
                                                   float* __restrict__ kpart,
                                                   unsigned* __restrict__ ticket) {
    const int bid = blockIdx.x, tid = threadIdx.x;
    const int wave = tid >> 6, lane = tid & 63;
    const int row = bid * 4 + wave;

    const float* p = feat + (size_t)row * D_FEAT + lane * 8;
    float4 a = *(const float4*)p;
    float4 b = *(const float4*)(p + 4);
    float vals[8] = {a.x, a.y, a.z, a.w, b.x, b.y, b.z, b.w};
    short outv[8];
    float s = 0.f;
#pragma unroll
    for (int j = 0; j < 8; ++j) {
        __hip_bfloat16 h = __float2bfloat16(vals[j]);
        outv[j] = *(short*)&h;
        float xb = __bfloat162float(h);
        s = fmaf(xb, xb, s);
    }
    *(s16x8*)(featbf + (size_t)row * D_FEAT + lane * 8) = *(s16x8*)outv;
    s = waveReduceSum(s);
    if (lane == 0) sqn[row] = s;

    if (tid < 4) posmax[bid * 4 + tid] = 0u;
    else if (tid < 8) negminf[bid * 4 + tid - 4] = 1e12f;
    else if (tid == 8 && bid == 0) ticket[0] = 0u;  // reset every launch (graph-replay safe)

    if (bid < 16) {
        int i = bid * 256 + tid;
        float l0 = logits[2 * i], l1 = logits[2 * i + 1];

        float m = fmaxf(l0, l1);
        float lse = m + logf(expf(l0 - m) + expf(l1 - m));
        float lp = (labels[i] ? l1 : l0) - lse;
        float ce = -lp;
        float pt = expf(lp);
        float om = 1.f - pt;
        float focal = om * om * ce;

        const float Tinv = 1.f / 3.f;
        float s0 = l0 * Tinv, s1 = l1 * Tinv;
        float ms = fmaxf(s0, s1);
        float lses = ms + logf(expf(s0 - ms) + expf(s1 - ms));
        float sl0 = s0 - lses, sl1 = s1 - lses;
        float t0 = logf(soft[2 * i] + 1e-8f) * Tinv;
        float t1 = logf(soft[2 * i + 1] + 1e-8f) * Tinv;
        float mt = fmaxf(t0, t1);
        float lset = mt + logf(expf(t0 - mt) + expf(t1 - mt));
        float tl0 = t0 - lset, tl1 = t1 - lset;
        float p0 = expf(tl0), p1 = expf(tl1);
        float kd = p0 * (tl0 - sl0) + p1 * (tl1 - sl1);

        float fs = waveReduceSum(focal);
        float ks = waveReduceSum(kd);
        __shared__ float sf[4], sk[4];
        if (lane == 0) { sf[wave] = fs; sk[wave] = ks; }
        __syncthreads();
        if (tid == 0) {
            fpart[bid] = sf[0] + sf[1] + sf[2] + sf[3];
            kpart[bid] = sk[0] + sk[1] + sk[2] + sk[3];
        }
    }
}

// ---- pairwise d^2, 256x256 tile, 8 waves (2Mx4N), BK=64, 8-phase (4/K-tile)
// counted-vmcnt schedule (T3+T4) + setprio (T5) — round-9 verified structure —
// PLUS fused final combine: last block (device-scope ticket) reduces posmax/negmin
// and writes the 4 outputs (removes the finalize dispatch).
__global__ __launch_bounds__(512) void pairwise_8ph_kernel(const short* __restrict__ featbf,
                                                           const float* __restrict__ sqn,
                                                           const int* __restrict__ labels,
                                                           unsigned* __restrict__ posmax,
                                                           unsigned* __restrict__ negmin,
                                                           const float* __restrict__ fpart,
                                                           const float* __restrict__ kpart,
                                                           unsigned* __restrict__ ticket,
                                                           float* __restrict__ out) {
    __shared__ short As0[256 * 64], As1[256 * 64];
    __shared__ short Bs0[256 * 64], Bs1[256 * 64];
    __shared__ unsigned rank_s;
    const int tid = threadIdx.x;
    const int bfl = blockIdx.x;
    const int xcd = bfl & 7, loc = bfl >> 3;
    const int ib = (xcd & 3) * 4 + (loc & 3);
    const int jb = ((xcd >> 1) & 2) * 4 + (loc >> 2);
    const int wid = tid >> 6, lane = tid & 63;
    const int wr = wid >> 2, wc = wid & 3;
    const int lo = lane & 15, hi = lane >> 4;

    // ---- staging addressing ----
    const int rbA0 = (wid < 4) ? wid * 16 : 64 + wid * 16;  // a0 row-base per wave
    const int rbB0 = wid * 16;                              // b0 row-base
    const int rA0 = rbA0 + (lane >> 2), rA1 = rA0 + 64;
    const int rB0 = rbB0 + (lane >> 2), rB1 = rB0 + 128;
    const int cA0 = (lane & 3) ^ ((rA0 >> 1) & 3), cA1 = (lane & 3) ^ ((rA1 >> 1) & 3);
    const int cB0 = (lane & 3) ^ ((rB0 >> 1) & 3), cB1 = (lane & 3) ^ ((rB1 >> 1) & 3);
    const short* gA0 = featbf + (size_t)(ib * 256 + rA0) * D_FEAT + cA0 * 8;
    const short* gA1 = featbf + (size_t)(ib * 256 + rA1) * D_FEAT + cA1 * 8;
    const short* gB0 = featbf + (size_t)(jb * 256 + rB0) * D_FEAT + cB0 * 8;
    const short* gB1 = featbf + (size_t)(jb * 256 + rB1) * D_FEAT + cB1 * 8;
    const int dA0 = rbA0 * 32, dA1 = (rbA0 + 64) * 32;   // LDS short-offsets (+ks*8192)
    const int dB0 = rbB0 * 32, dB1 = (rbB0 + 128) * 32;

#define ISSUE(gptr, buf, dstbase, ksv, ktv)                                            \
    GLOAD_LDS16((gptr) + (ktv) * 64 + (ksv) * 32, (buf) + (ksv) * 8192 + (dstbase))

    // ---- fragment ds_read offsets (shorts; + ks*8192) ----
    int aoffs[8], boffs[4];
#pragma unroll
    for (int m = 0; m < 8; ++m) {
        int r = wr * 128 + m * 16 + lo;
        aoffs[m] = r * 32 + ((hi ^ ((r >> 1) & 3)) * 8);
    }
#pragma unroll
    for (int n = 0; n < 4; ++n) {
        int r = wc * 64 + n * 16 + lo;
        boffs[n] = r * 32 + ((hi ^ ((r >> 1) & 3)) * 8);
    }

    f32x4 acc[8][4];
#pragma unroll
    for (int m = 0; m < 8; ++m)
#pragma unroll
        for (int n = 0; n < 4; ++n)
            acc[m][n] = (f32x4){0.f, 0.f, 0.f, 0.f};

#define PHASE(mh, ksv, DO_BFR, ISSUES, VMCNT)                                          \
    {                                                                                  \
        if (DO_BFR) {                                                                  \
            _Pragma("unroll") for (int n = 0; n < 4; ++n)                              \
                bfr[n] = *(const s16x8*)(Bcur + (ksv) * 8192 + boffs[n]);              \
        }                                                                              \
        s16x8 af[4];                                                                   \
        _Pragma("unroll") for (int mi = 0; mi < 4; ++mi)                               \
            af[mi] = *(const s16x8*)(Acur + (ksv) * 8192 + aoffs[(mh) * 4 + mi]);      \
        ISSUES;                                                                        \
        __builtin_amdgcn_s_barrier();                                                  \
        __builtin_amdgcn_sched_barrier(0);                                             \
        __builtin_amdgcn_s_setprio(1);                                                 \
        _Pragma("unroll") for (int mi = 0; mi < 4; ++mi)                               \
            _Pragma("unroll") for (int n = 0; n < 4; ++n)                              \
                acc[(mh) * 4 + mi][n] = __builtin_amdgcn_mfma_f32_16x16x32_bf16(       \
                    af[mi], bfr[n], acc[(mh) * 4 + mi][n], 0, 0, 0);                   \
        __builtin_amdgcn_s_setprio(0);                                                 \
        VMCNT;                                                                         \
        __builtin_amdgcn_s_barrier();                                                  \
        __builtin_amdgcn_sched_barrier(0);                                             \
    }

#define VM(n) asm volatile("s_waitcnt vmcnt(" #n ")" ::: "memory")

    const short* Acur = As0;
    const short* Bcur = Bs0;
    short* Anxt = As1;
    short* Bnxt = Bs1;

    // prologue: tile 0 chunks in ledger order a0,b0,b1,a1,a2,b2,b3,a3
    ISSUE(gA0, As0, dA0, 0, 0);
    ISSUE(gB0, Bs0, dB0, 0, 0);
    ISSUE(gB1, Bs0, dB1, 0, 0);
    ISSUE(gA1, As0, dA1, 0, 0);
    ISSUE(gA0, As0, dA0, 1, 0);
    ISSUE(gB0, Bs0, dB0, 1, 0);
    ISSUE(gB1, Bs0, dB1, 1, 0);
    ISSUE(gA1, As0, dA1, 1, 0);
    VM(5);  // a0,b0,b1 landed (all waves certify at next barrier)
    __builtin_amdgcn_s_barrier();
    __builtin_amdgcn_sched_barrier(0);

#pragma unroll 1
    for (int kt = 0; kt < D_FEAT / 64 - 1; ++kt) {
        s16x8 bfr[4];
        PHASE(0, 0, true,
              { ISSUE(gA0, Anxt, dA0, 0, kt + 1); ISSUE(gB0, Bnxt, dB0, 0, kt + 1); },
              VM(6));
        PHASE(1, 0, false,
              { ISSUE(gB1, Bnxt, dB1, 0, kt + 1); ISSUE(gA1, Anxt, dA1, 0, kt + 1); },
              VM(5));
        PHASE(0, 1, true,
              { ISSUE(gA0, Anxt, dA0, 1, kt + 1); ISSUE(gB0, Bnxt, dB0, 1, kt + 1); },
              VM(6));
        PHASE(1, 1, false,
              { ISSUE(gB1, Bnxt, dB1, 1, kt + 1); ISSUE(gA1, Anxt, dA1, 1, kt + 1); },
              VM(5));
        const short* t1 = Acur; Acur = Anxt; Anxt = (short*)t1;
        const short* t2 = Bcur; Bcur = Bnxt; Bnxt = (short*)t2;
    }
    {  // tail tile (no issues; drain)
        s16x8 bfr[4];
        PHASE(0, 0, true,  {}, VM(4));
        PHASE(1, 0, false, {}, VM(1));
        PHASE(0, 1, true,  {}, VM(0));
        PHASE(1, 1, false, {}, {});
    }

#undef PHASE
#undef VM
#undef ISSUE

    // ---- epilogue in d^2 domain (C/D layout m89: col = lo, row = hi*4 + reg) ----
    int coln[4], labc[4];
    float sqc[4];
#pragma unroll
    for (int n = 0; n < 4; ++n) {
        coln[n] = jb * 256 + wc * 64 + n * 16 + lo;
        labc[n] = labels[coln[n]];
        sqc[n] = sqn[coln[n]];
    }
    __syncthreads();  // K-loop fully done before LDS reuse
    float (*redp)[5] = (float(*)[5])As0;          // [256][5]
    float (*redn)[5] = ((float(*)[5])As0) + 256;  // [256][5]

#pragma unroll
    for (int m = 0; m < 8; ++m) {
#pragma unroll
        for (int r = 0; r < 4; ++r) {
            int row_loc = wr * 128 + m * 16 + hi * 4 + r;
            int row_g = ib * 256 + row_loc;
            int labr = labels[row_g];
            float sqr = sqn[row_g];
            float pm = 0.f, nm = 1e12f;
#pragma unroll
            for (int n = 0; n < 4; ++n) {
                float d2 = fmaxf(sqr + fmaf(-2.f, acc[m][n][r], sqc[n]), 0.f);
                bool same = (labr == labc[n]);
                if (same) {
                    if (row_g != coln[n]) pm = fmaxf(pm, d2);
                } else {
                    nm = fminf(nm, d2);
                }
            }
#pragma unroll
            for (int off = 1; off < 16; off <<= 1) {
                pm = fmaxf(pm, __shfl_xor(pm, off));
                nm = fminf(nm, __shfl_xor(nm, off));
            }
            if (lo == 0) {
                redp[row_loc][wc] = pm;
                redn[row_loc][wc] = nm;
            }
        }
    }
    __syncthreads();
    if (tid < 256) {
        float p = fmaxf(fmaxf(redp[tid][0], redp[tid][1]),
                        fmaxf(redp[tid][2], redp[tid][3]));
        atomicMax(&posmax[ib * 256 + tid], __float_as_uint(p));
    } else {
        int row = tid - 256;
        float nn = fminf(fminf(redn[row][0], redn[row][1]),
                         fminf(redn[row][2], redn[row][3]));
        atomicMin(&negmin[ib * 256 + row], __float_as_uint(nn));
    }

    // ---- fused finalize: last block does the global combine ----
    __syncthreads();  // drains this block's atomics (vmcnt(0) before s_barrier)
    if (tid == 0) {
        __threadfence();                       // order data atomics before ticket add
        rank_s = atomicAdd(ticket, 1u);        // device-scope
    }
    __syncthreads();
    if (rank_s == 255u) {  // all 256 blocks' atomics are ordered-before this point
        float sum_pr = 0.f, sum_v = 0.f;
        for (int i = tid; i < B_ROWS; i += 512) {
            unsigned pb = __hip_atomic_load(&posmax[i], __ATOMIC_RELAXED,
                                            __HIP_MEMORY_SCOPE_AGENT);
            unsigned nb = __hip_atomic_load(&negmin[i], __ATOMIC_RELAXED,
                                            __HIP_MEMORY_SCOPE_AGENT);
            float p2 = __uint_as_float(pb);
            float n2 = __uint_as_float(nb);
            float v = (p2 > 0.f) ? 1.f : 0.f;
            sum_pr += fmaxf(sqrtf(p2) - sqrtf(n2) + 0.3f, 0.f) * v;
            sum_v += v;
        }
        sum_pr = waveReduceSum(sum_pr);
        sum_v = waveReduceSum(sum_v);
        float* spv = (float*)As0;  // LDS reuse (post-barrier)
        if (lane == 0) { spv[wid] = sum_pr; spv[8 + wid] = sum_v; }
        __syncthreads();
        if (tid == 0) {
            float spr = 0.f, svv = 0.f;
#pragma unroll
            for (int w = 0; w < 8; ++w) { spr += spv[w]; svv += spv[8 + w]; }
            float fsum = 0.f, ksum = 0.f;
            for (int b = 0; b < 16; ++b) { fsum += fpart[b]; ksum += kpart[b]; }
            float focal = fsum / 4096.f;
            float kd = ksum / 4096.f * 9.f;  // * T^2
            float triplet = (svv > 0.f) ? spr / fmaxf(svv, 1.f) : 0.f;
            float total = focal + 0.5f * triplet + kd;
            out[0] = total;
            out[1] = focal;
            out[2] = triplet;
            out[3] = kd;
        }
    }
}

extern "C" void kernel_launch(void* const* d_in, const int* in_sizes, int n_in,
                              void* d_out, int out_size, void* d_ws, size_t ws_size,
                              hipStream_t stream) {
    const float* logits = (const float*)d_in[0];
    const float* feat   = (const float*)d_in[1];
    const int*   labels = (const int*)d_in[2];
    const float* soft   = (const float*)d_in[3];

    char* ws = (char*)d_ws;
    unsigned* posmax = (unsigned*)ws;                    // 4096 u32 (d^2 bits)
    unsigned* negmin = (unsigned*)(ws + 16384);          // 4096 u32 (d^2 bits)
    float*    sqn    = (float*)(ws + 32768);             // 4096 f32
    float*    fpart  = (float*)(ws + 49152);             // 16 f32
    float*    kpart  = (float*)(ws + 49152 + 256);       // 16 f32
    unsigned* ticket = (unsigned*)(ws + 49152 + 512);    // 1 u32
    short*    featbf = (short*)(ws + 65536);             // 4096*512 bf16 = 4 MB

    prep_kernel<<<1024, 256, 0, stream>>>(feat, logits, labels, soft, featbf, sqn,
                                          posmax, (float*)negmin, fpart, kpart, ticket);
    pairwise_8ph_kernel<<<256, 512, 0, stream>>>(featbf, sqn, labels, posmax, negmin,
                                                 fpart, kpart, ticket, (float*)d_out);
}

// Round 14
// 41.905 us; speedup vs baseline: 2.1879x; 1.0630x over previous
//
#include <hip/hip_runtime.h>
#include <hip/hip_bf16.h>

#define B_ROWS 4096
#define D_FEAT 512

typedef short s16x8 __attribute__((ext_vector_type(8)));
typedef float f32x4 __attribute__((ext_vector_type(4)));

#define GLOAD_LDS16(gsrc, ldst)                                                        \
    __builtin_amdgcn_global_load_lds(                                                  \
        (const __attribute__((address_space(1))) void*)(gsrc),                         \
        (__attribute__((address_space(3))) void*)(ldst), 16, 0, 0)

__device__ inline float waveReduceSum(float v) {
#pragma unroll
    for (int off = 32; off > 0; off >>= 1) v += __shfl_xor(v, off);
    return v;
}

// ---- prep: fp32->bf16 convert + sqnorm(rounded) + ws init; blocks 0..15 also do focal+KD ----
__global__ __launch_bounds__(256) void prep_kernel(const float* __restrict__ feat,
                                                   const float* __restrict__ logits,
                                                   const int* __restrict__ labels,
                                                   const float* __restrict__ soft,
                                                   short* __restrict__ featbf,
                                                   float* __restrict__ sqn,
                                                   unsigned* __restrict__ posmax,
                                                   float* __restrict__ negminf,
                                                   float* __restrict__ fpart,
                                                   float* __restrict__ kpart) {
    const int bid = blockIdx.x, tid = threadIdx.x;
    const int wave = tid >> 6, lane = tid & 63;
    const int row = bid * 4 + wave;

    const float* p = feat + (size_t)row * D_FEAT + lane * 8;
    float4 a = *(const float4*)p;
    float4 b = *(const float4*)(p + 4);
    float vals[8] = {a.x, a.y, a.z, a.w, b.x, b.y, b.z, b.w};
    short outv[8];
    float s = 0.f;
#pragma unroll
    for (int j = 0; j < 8; ++j) {
        __hip_bfloat16 h = __float2bfloat16(vals[j]);
        outv[j] = *(short*)&h;
        float xb = __bfloat162float(h);
        s = fmaf(xb, xb, s);
    }
    *(s16x8*)(featbf + (size_t)row * D_FEAT + lane * 8) = *(s16x8*)outv;
    s = waveReduceSum(s);
    if (lane == 0) sqn[row] = s;

    if (tid < 4) posmax[bid * 4 + tid] = 0u;
    else if (tid < 8) negminf[bid * 4 + tid - 4] = 1e12f;

    if (bid < 16) {
        int i = bid * 256 + tid;
        float l0 = logits[2 * i], l1 = logits[2 * i + 1];

        float m = fmaxf(l0, l1);
        float lse = m + logf(expf(l0 - m) + expf(l1 - m));
        float lp = (labels[i] ? l1 : l0) - lse;
        float ce = -lp;
        float pt = expf(lp);
        float om = 1.f - pt;
        float focal = om * om * ce;

        const float Tinv = 1.f / 3.f;
        float s0 = l0 * Tinv, s1 = l1 * Tinv;
        float ms = fmaxf(s0, s1);
        float lses = ms + logf(expf(s0 - ms) + expf(s1 - ms));
        float sl0 = s0 - lses, sl1 = s1 - lses;
        float t0 = logf(soft[2 * i] + 1e-8f) * Tinv;
        float t1 = logf(soft[2 * i + 1] + 1e-8f) * Tinv;
        float mt = fmaxf(t0, t1);
        float lset = mt + logf(expf(t0 - mt) + expf(t1 - mt));
        float tl0 = t0 - lset, tl1 = t1 - lset;
        float p0 = expf(tl0), p1 = expf(tl1);
        float kd = p0 * (tl0 - sl0) + p1 * (tl1 - sl1);

        float fs = waveReduceSum(focal);
        float ks = waveReduceSum(kd);
        __shared__ float sf[4], sk[4];
        if (lane == 0) { sf[wave] = fs; sk[wave] = ks; }
        __syncthreads();
        if (tid == 0) {
            fpart[bid] = sf[0] + sf[1] + sf[2] + sf[3];
            kpart[bid] = sk[0] + sk[1] + sk[2] + sk[3];
        }
    }
}

// ---- pairwise d^2, 256x256 tile, **16 waves (4Mx4N, 1024 thr)**, BK=64,
// 2 fat phases per K-tile, counted-vmcnt (T4) + setprio (T5).
// Rationale: r9 ran 2 waves/SIMD -> dependent-chain stalls uncovered (MfmaUtil 13%).
// 16 waves = 4 waves/SIMD, wave tile 64x64 (acc 64 AGPR -> fits 128-reg cap).
// LDS per buffer: [ks(2)][row(256)][c4(4) x 16B], swizzle c4' = c4 ^ ((row>>1)&3);
// staging issue = 1 gload_lds per wave (wave w covers rows w*16..w*16+15), 4
// issues/K-tile: A-ks0, B-ks0, A-ks1, B-ks1.
// Ledger (1 instr/wave per issue): prologue 4 issues, VM(2); steady phases issue 2,
// VM(2); tail VM(0), none.
__global__ __launch_bounds__(1024) void pairwise_16w_kernel(const short* __restrict__ featbf,
                                                            const float* __restrict__ sqn,
                                                            const int* __restrict__ labels,
                                                            unsigned* __restrict__ posmax,
                                                            unsigned* __restrict__ negmin) {
    __shared__ short As0[256 * 64], As1[256 * 64];
    __shared__ short Bs0[256 * 64], Bs1[256 * 64];
    const int tid = threadIdx.x;
    const int bfl = blockIdx.x;
    const int xcd = bfl & 7, loc = bfl >> 3;
    const int ib = (xcd & 3) * 4 + (loc & 3);
    const int jb = ((xcd >> 1) & 2) * 4 + (loc >> 2);
    const int wid = tid >> 6, lane = tid & 63;
    const int wr = wid >> 2, wc = wid & 3;    // 4 x 4 wave grid
    const int lo = lane & 15, hi = lane >> 4;

    // ---- staging addressing: wave w stages rows w*16..w*16+15 of a 256x64 half ----
    const int srow = wid * 16 + (lane >> 2);              // 0..255
    const int sc = (lane & 3) ^ ((srow >> 1) & 3);        // swizzled source c4
    const short* gA = featbf + (size_t)(ib * 256 + srow) * D_FEAT + sc * 8;
    const short* gB = featbf + (size_t)(jb * 256 + srow) * D_FEAT + sc * 8;
    const int dst = wid * 512;  // short offset of wave's row base (+ks*8192)

#define ISSUE(gptr, buf, ksv, ktv)                                                     \
    GLOAD_LDS16((gptr) + (ktv) * 64 + (ksv) * 32, (buf) + (ksv) * 8192 + dst)

    // ---- fragment ds_read offsets (shorts; + ks*8192), same involution ----
    int aoffs[4], boffs[4];
#pragma unroll
    for (int m = 0; m < 4; ++m) {
        int r = wr * 64 + m * 16 + lo;
        aoffs[m] = r * 32 + ((hi ^ ((r >> 1) & 3)) * 8);
    }
#pragma unroll
    for (int n = 0; n < 4; ++n) {
        int r = wc * 64 + n * 16 + lo;
        boffs[n] = r * 32 + ((hi ^ ((r >> 1) & 3)) * 8);
    }

    f32x4 acc[4][4];
#pragma unroll
    for (int m = 0; m < 4; ++m)
#pragma unroll
        for (int n = 0; n < 4; ++n)
            acc[m][n] = (f32x4){0.f, 0.f, 0.f, 0.f};

#define PHASE(ksv, ISSUES, VMCNT)                                                      \
    {                                                                                  \
        s16x8 af[4], bfr[4];                                                           \
        _Pragma("unroll") for (int n = 0; n < 4; ++n)                                  \
            bfr[n] = *(const s16x8*)(Bcur + (ksv) * 8192 + boffs[n]);                  \
        _Pragma("unroll") for (int m = 0; m < 4; ++m)                                  \
            af[m] = *(const s16x8*)(Acur + (ksv) * 8192 + aoffs[m]);                   \
        ISSUES;                                                                        \
        __builtin_amdgcn_s_barrier();                                                  \
        __builtin_amdgcn_sched_barrier(0);                                             \
        __builtin_amdgcn_s_setprio(1);                                                 \
        _Pragma("unroll") for (int m = 0; m < 4; ++m)                                  \
            _Pragma("unroll") for (int n = 0; n < 4; ++n)                              \
                acc[m][n] = __builtin_amdgcn_mfma_f32_16x16x32_bf16(                   \
                    af[m], bfr[n], acc[m][n], 0, 0, 0);                                \
        __builtin_amdgcn_s_setprio(0);                                                 \
        VMCNT;                                                                         \
        __builtin_amdgcn_s_barrier();                                                  \
        __builtin_amdgcn_sched_barrier(0);                                             \
    }

#define VM(n) asm volatile("s_waitcnt vmcnt(" #n ")" ::: "memory")

    const short* Acur = As0;
    const short* Bcur = Bs0;
    short* Anxt = As1;
    short* Bnxt = Bs1;

    // prologue: tile 0 — A-ks0, B-ks0, A-ks1, B-ks1
    ISSUE(gA, As0, 0, 0);
    ISSUE(gB, Bs0, 0, 0);
    ISSUE(gA, As0, 1, 0);
    ISSUE(gB, Bs0, 1, 0);
    VM(2);  // A-ks0, B-ks0 landed (barrier certifies all waves' parts)
    __builtin_amdgcn_s_barrier();
    __builtin_amdgcn_sched_barrier(0);

#pragma unroll 1
    for (int kt = 0; kt < D_FEAT / 64 - 1; ++kt) {
        PHASE(0, { ISSUE(gA, Anxt, 0, kt + 1); ISSUE(gB, Bnxt, 0, kt + 1); }, VM(2));
        PHASE(1, { ISSUE(gA, Anxt, 1, kt + 1); ISSUE(gB, Bnxt, 1, kt + 1); }, VM(2));
        const short* t1 = Acur; Acur = Anxt; Anxt = (short*)t1;
        const short* t2 = Bcur; Bcur = Bnxt; Bnxt = (short*)t2;
    }
    {  // tail tile: no issues; drain
        PHASE(0, {}, VM(0));
        PHASE(1, {}, {});
    }

#undef PHASE
#undef VM
#undef ISSUE

    // ---- epilogue in d^2 domain (C/D layout m89: col = lo, row = hi*4 + reg) ----
    int coln[4], labc[4];
    float sqc[4];
#pragma unroll
    for (int n = 0; n < 4; ++n) {
        coln[n] = jb * 256 + wc * 64 + n * 16 + lo;
        labc[n] = labels[coln[n]];
        sqc[n] = sqn[coln[n]];
    }
    __syncthreads();  // K-loop fully done before LDS reuse
    float (*redp)[5] = (float(*)[5])As0;          // [256][5]
    float (*redn)[5] = ((float(*)[5])As0) + 256;  // [256][5]

#pragma unroll
    for (int m = 0; m < 4; ++m) {
#pragma unroll
        for (int r = 0; r < 4; ++r) {
            int row_loc = wr * 64 + m * 16 + hi * 4 + r;
            int row_g = ib * 256 + row_loc;
            int labr = labels[row_g];
            float sqr = sqn[row_g];
            float pm = 0.f, nm = 1e12f;
#pragma unroll
            for (int n = 0; n < 4; ++n) {
                float d2 = fmaxf(sqr + fmaf(-2.f, acc[m][n][r], sqc[n]), 0.f);
                bool same = (labr == labc[n]);
                if (same) {
                    if (row_g != coln[n]) pm = fmaxf(pm, d2);
                } else {
                    nm = fminf(nm, d2);
                }
            }
#pragma unroll
            for (int off = 1; off < 16; off <<= 1) {
                pm = fmaxf(pm, __shfl_xor(pm, off));
                nm = fminf(nm, __shfl_xor(nm, off));
            }
            if (lo == 0) {
                redp[row_loc][wc] = pm;
                redn[row_loc][wc] = nm;
            }
        }
    }
    __syncthreads();
    if (tid < 256) {
        float p = fmaxf(fmaxf(redp[tid][0], redp[tid][1]),
                        fmaxf(redp[tid][2], redp[tid][3]));
        atomicMax(&posmax[ib * 256 + tid], __float_as_uint(p));
    } else if (tid < 512) {
        int row = tid - 256;
        float nn = fminf(fminf(redn[row][0], redn[row][1]),
                         fminf(redn[row][2], redn[row][3]));
        atomicMin(&negmin[ib * 256 + row], __float_as_uint(nn));
    }
}

// ---- final reduction + scalar combine (sqrt deferred to here; float32 outputs) ----
__global__ __launch_bounds__(256) void finalize_kernel(const unsigned* __restrict__ posmax,
                                                       const unsigned* __restrict__ negmin,
                                                       const float* __restrict__ fpart,
                                                       const float* __restrict__ kpart,
                                                       float* __restrict__ out) {
    int tid = threadIdx.x;
    float sum_pr = 0.f, sum_v = 0.f;
    for (int i = tid; i < B_ROWS; i += 256) {
        float p2 = __uint_as_float(posmax[i]);
        float n2 = __uint_as_float(negmin[i]);
        float v = (p2 > 0.f) ? 1.f : 0.f;
        sum_pr += fmaxf(sqrtf(p2) - sqrtf(n2) + 0.3f, 0.f) * v;
        sum_v += v;
    }
    sum_pr = waveReduceSum(sum_pr);
    sum_v = waveReduceSum(sum_v);
    __shared__ float sp[4], sv[4];
    int wave = tid >> 6, lane = tid & 63;
    if (lane == 0) { sp[wave] = sum_pr; sv[wave] = sum_v; }
    __syncthreads();
    if (tid == 0) {
        float spr = sp[0] + sp[1] + sp[2] + sp[3];
        float svv = sv[0] + sv[1] + sv[2] + sv[3];
        float fsum = 0.f, ksum = 0.f;
        for (int b = 0; b < 16; ++b) { fsum += fpart[b]; ksum += kpart[b]; }
        float focal = fsum / 4096.f;
        float kd = ksum / 4096.f * 9.f;  // * T^2
        float triplet = (svv > 0.f) ? spr / fmaxf(svv, 1.f) : 0.f;
        float total = focal + 0.5f * triplet + kd;
        out[0] = total;
        out[1] = focal;
        out[2] = triplet;
        out[3] = kd;
    }
}

extern "C" void kernel_launch(void* const* d_in, const int* in_sizes, int n_in,
                              void* d_out, int out_size, void* d_ws, size_t ws_size,
                              hipStream_t stream) {
    const float* logits = (const float*)d_in[0];
    const float* feat   = (const float*)d_in[1];
    const int*   labels = (const int*)d_in[2];
    const float* soft   = (const float*)d_in[3];

    char* ws = (char*)d_ws;
    unsigned* posmax = (unsigned*)ws;                    // 4096 u32 (d^2 bits)
    unsigned* negmin = (unsigned*)(ws + 16384);          // 4096 u32 (d^2 bits)
    float*    sqn    = (float*)(ws + 32768);             // 4096 f32
    float*    fpart  = (float*)(ws + 49152);             // 16 f32
    float*    kpart  = (float*)(ws + 49152 + 256);       // 16 f32
    short*    featbf = (short*)(ws + 65536);             // 4096*512 bf16 = 4 MB

    prep_kernel<<<1024, 256, 0, stream>>>(feat, logits, labels, soft, featbf, sqn,
                                          posmax, (float*)negmin, fpart, kpart);
    pairwise_16w_kernel<<<256, 1024, 0, stream>>>(featbf, sqn, labels, posmax, negmin);
    finalize_kernel<<<1, 256, 0, stream>>>(posmax, negmin, fpart, kpart,
                                           (float*)d_out);
}

// Round 15
// 40.400 us; speedup vs baseline: 2.2694x; 1.0373x over previous
//
#include <hip/hip_runtime.h>
#include <hip/hip_bf16.h>

#define B_ROWS 4096
#define D_FEAT 512

typedef short s16x8 __attribute__((ext_vector_type(8)));
typedef float f32x4 __attribute__((ext_vector_type(4)));

#define GLOAD_LDS16(gsrc, ldst)                                                        \
    __builtin_amdgcn_global_load_lds(                                                  \
        (const __attribute__((address_space(1))) void*)(gsrc),                         \
        (__attribute__((address_space(3))) void*)(ldst), 16, 0, 0)

__device__ inline float waveReduceSum(float v) {
#pragma unroll
    for (int off = 32; off > 0; off >>= 1) v += __shfl_xor(v, off);
    return v;
}

// ---- prep: fp32->bf16 convert + sqnorm(rounded) + ws init; blocks 0..15 also do focal+KD ----
__global__ __launch_bounds__(256) void prep_kernel(const float* __restrict__ feat,
                                                   const float* __restrict__ logits,
                                                   const int* __restrict__ labels,
                                                   const float* __restrict__ soft,
                                                   short* __restrict__ featbf,
                                                   float* __restrict__ sqn,
                                                   unsigned* __restrict__ posmax,
                                                   float* __restrict__ negminf,
                                                   float* __restrict__ fpart,
                                                   float* __restrict__ kpart) {
    const int bid = blockIdx.x, tid = threadIdx.x;
    const int wave = tid >> 6, lane = tid & 63;
    const int row = bid * 4 + wave;

    const float* p = feat + (size_t)row * D_FEAT + lane * 8;
    float4 a = *(const float4*)p;
    float4 b = *(const float4*)(p + 4);
    float vals[8] = {a.x, a.y, a.z, a.w, b.x, b.y, b.z, b.w};
    short outv[8];
    float s = 0.f;
#pragma unroll
    for (int j = 0; j < 8; ++j) {
        __hip_bfloat16 h = __float2bfloat16(vals[j]);
        outv[j] = *(short*)&h;
        float xb = __bfloat162float(h);
        s = fmaf(xb, xb, s);
    }
    *(s16x8*)(featbf + (size_t)row * D_FEAT + lane * 8) = *(s16x8*)outv;
    s = waveReduceSum(s);
    if (lane == 0) sqn[row] = s;

    if (tid < 4) posmax[bid * 4 + tid] = 0u;
    else if (tid < 8) negminf[bid * 4 + tid - 4] = 1e12f;

    if (bid < 16) {
        int i = bid * 256 + tid;
        float l0 = logits[2 * i], l1 = logits[2 * i + 1];

        float m = fmaxf(l0, l1);
        float lse = m + logf(expf(l0 - m) + expf(l1 - m));
        float lp = (labels[i] ? l1 : l0) - lse;
        float ce = -lp;
        float pt = expf(lp);
        float om = 1.f - pt;
        float focal = om * om * ce;

        const float Tinv = 1.f / 3.f;
        float s0 = l0 * Tinv, s1 = l1 * Tinv;
        float ms = fmaxf(s0, s1);
        float lses = ms + logf(expf(s0 - ms) + expf(s1 - ms));
        float sl0 = s0 - lses, sl1 = s1 - lses;
        float t0 = logf(soft[2 * i] + 1e-8f) * Tinv;
        float t1 = logf(soft[2 * i + 1] + 1e-8f) * Tinv;
        float mt = fmaxf(t0, t1);
        float lset = mt + logf(expf(t0 - mt) + expf(t1 - mt));
        float tl0 = t0 - lset, tl1 = t1 - lset;
        float p0 = expf(tl0), p1 = expf(tl1);
        float kd = p0 * (tl0 - sl0) + p1 * (tl1 - sl1);

        float fs = waveReduceSum(focal);
        float ks = waveReduceSum(kd);
        __shared__ float sf[4], sk[4];
        if (lane == 0) { sf[wave] = fs; sk[wave] = ks; }
        __syncthreads();
        if (tid == 0) {
            fpart[bid] = sf[0] + sf[1] + sf[2] + sf[3];
            kpart[bid] = sk[0] + sk[1] + sk[2] + sk[3];
        }
    }
}

// ---- pairwise d^2, 256x256 tile, 16 waves (4Mx4N, 1024 thr), BK=64,
// 2 fat phases per K-tile, counted-vmcnt (T4) + setprio (T5),
// **single barrier per phase** (r15): the pre-MFMA barrier is redundant —
// phase P's operands were certified by phase P-1's VM+barrier, and in-phase
// gload_lds targets only buf_next, so max wave skew (1 phase) < buffer
// lifetime (2 phases). sched_barrier pins dropped (m141): the "memory"
// clobber on VM() is the only fence needed (no inline-asm ds_read -> rule
// #18 doesn't apply).
// Ledger unchanged from r14: prologue 4 issues, VM(2); steady phases issue 2,
// VM(2) -> the 2 oldest outstanding (next phase's chunks) land; tail VM(0), none.
__global__ __launch_bounds__(1024) void pairwise_16w_kernel(const short* __restrict__ featbf,
                                                            const float* __restrict__ sqn,
                                                            const int* __restrict__ labels,
                                                            unsigned* __restrict__ posmax,
                                                            unsigned* __restrict__ negmin) {
    __shared__ short As0[256 * 64], As1[256 * 64];
    __shared__ short Bs0[256 * 64], Bs1[256 * 64];
    const int tid = threadIdx.x;
    const int bfl = blockIdx.x;
    const int xcd = bfl & 7, loc = bfl >> 3;
    const int ib = (xcd & 3) * 4 + (loc & 3);
    const int jb = ((xcd >> 1) & 2) * 4 + (loc >> 2);
    const int wid = tid >> 6, lane = tid & 63;
    const int wr = wid >> 2, wc = wid & 3;    // 4 x 4 wave grid
    const int lo = lane & 15, hi = lane >> 4;

    // ---- staging addressing: wave w stages rows w*16..w*16+15 of a 256x64 half ----
    const int srow = wid * 16 + (lane >> 2);              // 0..255
    const int sc = (lane & 3) ^ ((srow >> 1) & 3);        // swizzled source c4
    const short* gA = featbf + (size_t)(ib * 256 + srow) * D_FEAT + sc * 8;
    const short* gB = featbf + (size_t)(jb * 256 + srow) * D_FEAT + sc * 8;
    const int dst = wid * 512;  // short offset of wave's row base (+ks*8192)

#define ISSUE(gptr, buf, ksv, ktv)                                                     \
    GLOAD_LDS16((gptr) + (ktv) * 64 + (ksv) * 32, (buf) + (ksv) * 8192 + dst)

    // ---- fragment ds_read offsets (shorts; + ks*8192), same involution ----
    int aoffs[4], boffs[4];
#pragma unroll
    for (int m = 0; m < 4; ++m) {
        int r = wr * 64 + m * 16 + lo;
        aoffs[m] = r * 32 + ((hi ^ ((r >> 1) & 3)) * 8);
    }
#pragma unroll
    for (int n = 0; n < 4; ++n) {
        int r = wc * 64 + n * 16 + lo;
        boffs[n] = r * 32 + ((hi ^ ((r >> 1) & 3)) * 8);
    }

    f32x4 acc[4][4];
#pragma unroll
    for (int m = 0; m < 4; ++m)
#pragma unroll
        for (int n = 0; n < 4; ++n)
            acc[m][n] = (f32x4){0.f, 0.f, 0.f, 0.f};

#define PHASE(ksv, ISSUES, VMCNT, DO_BAR)                                              \
    {                                                                                  \
        s16x8 af[4], bfr[4];                                                           \
        _Pragma("unroll") for (int n = 0; n < 4; ++n)                                  \
            bfr[n] = *(const s16x8*)(Bcur + (ksv) * 8192 + boffs[n]);                  \
        _Pragma("unroll") for (int m = 0; m < 4; ++m)                                  \
            af[m] = *(const s16x8*)(Acur + (ksv) * 8192 + aoffs[m]);                   \
        ISSUES;                                                                        \
        __builtin_amdgcn_s_setprio(1);                                                 \
        _Pragma("unroll") for (int m = 0; m < 4; ++m)                                  \
            _Pragma("unroll") for (int n = 0; n < 4; ++n)                              \
                acc[m][n] = __builtin_amdgcn_mfma_f32_16x16x32_bf16(                   \
                    af[m], bfr[n], acc[m][n], 0, 0, 0);                                \
        __builtin_amdgcn_s_setprio(0);                                                 \
        VMCNT;                                                                         \
        if (DO_BAR) __builtin_amdgcn_s_barrier();                                      \
    }

#define VM(n) asm volatile("s_waitcnt vmcnt(" #n ")" ::: "memory")

    const short* Acur = As0;
    const short* Bcur = Bs0;
    short* Anxt = As1;
    short* Bnxt = Bs1;

    // prologue: tile 0 — A-ks0, B-ks0, A-ks1, B-ks1
    ISSUE(gA, As0, 0, 0);
    ISSUE(gB, Bs0, 0, 0);
    ISSUE(gA, As0, 1, 0);
    ISSUE(gB, Bs0, 1, 0);
    VM(2);  // A-ks0, B-ks0 landed (barrier certifies all waves' parts)
    __builtin_amdgcn_s_barrier();

#pragma unroll 1
    for (int kt = 0; kt < D_FEAT / 64 - 1; ++kt) {
        PHASE(0, { ISSUE(gA, Anxt, 0, kt + 1); ISSUE(gB, Bnxt, 0, kt + 1); }, VM(2), true);
        PHASE(1, { ISSUE(gA, Anxt, 1, kt + 1); ISSUE(gB, Bnxt, 1, kt + 1); }, VM(2), true);
        const short* t1 = Acur; Acur = Anxt; Anxt = (short*)t1;
        const short* t2 = Bcur; Bcur = Bnxt; Bnxt = (short*)t2;
    }
    {  // tail tile: no issues; drain
        PHASE(0, {}, VM(0), true);
        PHASE(1, {}, {}, false);
    }

#undef PHASE
#undef VM
#undef ISSUE

    // ---- epilogue in d^2 domain (C/D layout m89: col = lo, row = hi*4 + reg) ----
    int coln[4], labc[4];
    float sqc[4];
#pragma unroll
    for (int n = 0; n < 4; ++n) {
        coln[n] = jb * 256 + wc * 64 + n * 16 + lo;
        labc[n] = labels[coln[n]];
        sqc[n] = sqn[coln[n]];
    }
    __syncthreads();  // K-loop fully done before LDS reuse
    float (*redp)[5] = (float(*)[5])As0;          // [256][5]
    float (*redn)[5] = ((float(*)[5])As0) + 256;  // [256][5]

#pragma unroll
    for (int m = 0; m < 4; ++m) {
#pragma unroll
        for (int r = 0; r < 4; ++r) {
            int row_loc = wr * 64 + m * 16 + hi * 4 + r;
            int row_g = ib * 256 + row_loc;
            int labr = labels[row_g];
            float sqr = sqn[row_g];
            float pm = 0.f, nm = 1e12f;
#pragma unroll
            for (int n = 0; n < 4; ++n) {
                float d2 = fmaxf(sqr + fmaf(-2.f, acc[m][n][r], sqc[n]), 0.f);
                bool same = (labr == labc[n]);
                if (same) {
                    if (row_g != coln[n]) pm = fmaxf(pm, d2);
                } else {
                    nm = fminf(nm, d2);
                }
            }
#pragma unroll
            for (int off = 1; off < 16; off <<= 1) {
                pm = fmaxf(pm, __shfl_xor(pm, off));
                nm = fminf(nm, __shfl_xor(nm, off));
            }
            if (lo == 0) {
                redp[row_loc][wc] = pm;
                redn[row_loc][wc] = nm;
            }
        }
    }
    __syncthreads();
    if (tid < 256) {
        float p = fmaxf(fmaxf(redp[tid][0], redp[tid][1]),
                        fmaxf(redp[tid][2], redp[tid][3]));
        atomicMax(&posmax[ib * 256 + tid], __float_as_uint(p));
    } else if (tid < 512) {
        int row = tid - 256;
        float nn = fminf(fminf(redn[row][0], redn[row][1]),
                         fminf(redn[row][2], redn[row][3]));
        atomicMin(&negmin[ib * 256 + row], __float_as_uint(nn));
    }
}

// ---- final reduction + scalar combine (sqrt deferred to here; float32 outputs) ----
__global__ __launch_bounds__(256) void finalize_kernel(const unsigned* __restrict__ posmax,
                                                       const unsigned* __restrict__ negmin,
                                                       const float* __restrict__ fpart,
                                                       const float* __restrict__ kpart,
                                                       float* __restrict__ out) {
    int tid = threadIdx.x;
    float sum_pr = 0.f, sum_v = 0.f;
    for (int i = tid; i < B_ROWS; i += 256) {
        float p2 = __uint_as_float(posmax[i]);
        float n2 = __uint_as_float(negmin[i]);
        float v = (p2 > 0.f) ? 1.f : 0.f;
        sum_pr += fmaxf(sqrtf(p2) - sqrtf(n2) + 0.3f, 0.f) * v;
        sum_v += v;
    }
    sum_pr = waveReduceSum(sum_pr);
    sum_v = waveReduceSum(sum_v);
    __shared__ float sp[4], sv[4];
    int wave = tid >> 6, lane = tid & 63;
    if (lane == 0) { sp[wave] = sum_pr; sv[wave] = sum_v; }
    __syncthreads();
    if (tid == 0) {
        float spr = sp[0] + sp[1] + sp[2] + sp[3];
        float svv = sv[0] + sv[1] + sv[2] + sv[3];
        float fsum = 0.f, ksum = 0.f;
        for (int b = 0; b < 16; ++b) { fsum += fpart[b]; ksum += kpart[b]; }
        float focal = fsum / 4096.f;
        float kd = ksum / 4096.f * 9.f;  // * T^2
        float triplet = (svv > 0.f) ? spr / fmaxf(svv, 1.f) : 0.f;
        float total = focal + 0.5f * triplet + kd;
        out[0] = total;
        out[1] = focal;
        out[2] = triplet;
        out[3] = kd;
    }
}

extern "C" void kernel_launch(void* const* d_in, const int* in_sizes, int n_in,
                              void* d_out, int out_size, void* d_ws, size_t ws_size,
                              hipStream_t stream) {
    const float* logits = (const float*)d_in[0];
    const float* feat   = (const float*)d_in[1];
    const int*   labels = (const int*)d_in[2];
    const float* soft   = (const float*)d_in[3];

    char* ws = (char*)d_ws;
    unsigned* posmax = (unsigned*)ws;                    // 4096 u32 (d^2 bits)
    unsigned* negmin = (unsigned*)(ws + 16384);          // 4096 u32 (d^2 bits)
    float*    sqn    = (float*)(ws + 32768);             // 4096 f32
    float*    fpart  = (float*)(ws + 49152);             // 16 f32
    float*    kpart  = (float*)(ws + 49152 + 256);       // 16 f32
    short*    featbf = (short*)(ws + 65536);             // 4096*512 bf16 = 4 MB

    prep_kernel<<<1024, 256, 0, stream>>>(feat, logits, labels, soft, featbf, sqn,
                                          posmax, (float*)negmin, fpart, kpart);
    pairwise_16w_kernel<<<256, 1024, 0, stream>>>(featbf, sqn, labels, posmax, negmin);
    finalize_kernel<<<1, 256, 0, stream>>>(posmax, negmin, fpart, kpart,
                                           (float*)d_out);
}